// Round 8
// baseline (11585.119 us; speedup 1.0000x reference)
//
#include <hip/hip_runtime.h>

#define B_ 16
#define N_ 2048

typedef __attribute__((ext_vector_type(8))) short s16x8;
typedef __attribute__((ext_vector_type(4))) short s16x4;
typedef __attribute__((ext_vector_type(4))) float f32x4;

#define GLOAD16(gp, lp) __builtin_amdgcn_global_load_lds( \
    (const __attribute__((address_space(1))) void*)(gp),  \
    (__attribute__((address_space(3))) void*)(lp), 16, 0, 0)

__device__ inline unsigned short f2bf(float f) {
  unsigned u = __float_as_uint(f);
  u += 0x7FFFu + ((u >> 16) & 1u);
  return (unsigned short)(u >> 16);
}
__device__ inline float bf2f(unsigned short h) {
  return __uint_as_float(((unsigned)h) << 16);
}
__device__ inline float pget(const short* __restrict__ ph, const short* __restrict__ pl, long long i) {
  return bf2f((unsigned short)ph[i]) + bf2f((unsigned short)pl[i]);
}
__device__ inline void pput(short* __restrict__ ph, short* __restrict__ pl, long long i, float v) {
  unsigned short h = f2bf(v);
  ph[i] = (short)h;
  pl[i] = (short)f2bf(v - bf2f(h));
}

// ---------------- utility kernels ----------------

static __global__ void zerof_kernel(float* p, long long n) {
  long long i = (long long)blockIdx.x * blockDim.x + threadIdx.x;
  long long st = (long long)gridDim.x * blockDim.x;
  for (; i < n; i += st) p[i] = 0.f;
}

static __global__ void rowsq_small(const float* __restrict__ X, float* __restrict__ sq,
                                   int F, long long R) {
  long long i = (long long)blockIdx.x * blockDim.x + threadIdx.x;
  if (i >= R) return;
  const float* xr = X + i * F;
  float s = 0.f;
  for (int f = 0; f < F; ++f) s += xr[f] * xr[f];
  sq[i] = s;
}

static __global__ void dinv_from_deg(const float* __restrict__ deg, float* __restrict__ dinv, long long n) {
  long long i = (long long)blockIdx.x * blockDim.x + threadIdx.x;
  if (i >= n) return;
  float d = deg[i];
  dinv[i] = (d > 0.f) ? rsqrtf(d) : 0.f;
}

// in-place: L <- -L * dinv_r * dinv_j  (planes), N_=2048
static __global__ void scaleL_p(short* Lh, short* Ll, const float* __restrict__ dinv, long long total) {
  long long i = (long long)blockIdx.x * blockDim.x + threadIdx.x;
  long long st = (long long)gridDim.x * blockDim.x;
  for (; i < total; i += st) {
    int j = (int)(i & (N_ - 1));
    long long bn = i >> 11;
    float v = pget(Lh, Ll, i);
    v = -v * dinv[bn] * dinv[((bn >> 11) << 11) + j];
    pput(Lh, Ll, i, v);
  }
}

// f32 row-major -> planes
static __global__ void cvt_rm_kernel(const float* __restrict__ src, int lds,
                                     short* __restrict__ dh, short* __restrict__ dl,
                                     int ldd, long long R, int Cc) {
  long long total = R * Cc;
  long long i = (long long)blockIdx.x * blockDim.x + threadIdx.x;
  long long st = (long long)gridDim.x * blockDim.x;
  for (; i < total; i += st) {
    long long r = i / Cc; int c = (int)(i - r * Cc);
    pput(dh, dl, r * ldd + c, src[r * lds + c]);
  }
}

// f32 -> transposed planes (z-batched)
static __global__ void cvt_tr_kernel(const float* __restrict__ src, int lds, long long sS,
                                     short* __restrict__ dh, short* __restrict__ dl,
                                     long long ldd, long long sD, int R, int Cc) {
  int z = blockIdx.z;
  src += (long long)z * sS;
  dh += (long long)z * sD;
  dl += (long long)z * sD;
  __shared__ float tile[32][33];
  int r0 = blockIdx.y * 32, c0 = blockIdx.x * 32;
  int tx = threadIdx.x, ty = threadIdx.y;
#pragma unroll
  for (int i = 0; i < 32; i += 8) {
    int r = r0 + ty + i, cx = c0 + tx;
    tile[ty + i][tx] = (r < R && cx < Cc) ? src[(long long)r * lds + cx] : 0.f;
  }
  __syncthreads();
#pragma unroll
  for (int i = 0; i < 32; i += 8) {
    int cr = c0 + ty + i, rx = r0 + tx;
    if (cr < Cc && rx < R) pput(dh, dl, (long long)cr * ldd + rx, tile[tx][ty + i]);
  }
}

// plane->plane transpose
static __global__ void tr_pp_kernel(const short* __restrict__ sh, const short* __restrict__ sl,
                                    long long lds, short* __restrict__ dh, short* __restrict__ dl,
                                    int ldd, int R, long long Cc) {
  __shared__ short th[32][33], tl[32][33];
  int r0 = blockIdx.y * 32;
  long long c0 = (long long)blockIdx.x * 32;
  int tx = threadIdx.x, ty = threadIdx.y;
#pragma unroll
  for (int i = 0; i < 32; i += 8) {
    int r = r0 + ty + i;
    long long cx = c0 + tx;
    short vh = 0, vl = 0;
    if (r < R && cx < Cc) { vh = sh[(long long)r * lds + cx]; vl = sl[(long long)r * lds + cx]; }
    th[ty + i][tx] = vh;
    tl[ty + i][tx] = vl;
  }
  __syncthreads();
#pragma unroll
  for (int i = 0; i < 32; i += 8) {
    long long cr = c0 + ty + i;
    int rx = r0 + tx;
    if (cr < Cc && rx < R) {
      dh[cr * ldd + rx] = th[tx][ty + i];
      dl[cr * ldd + rx] = tl[tx][ty + i];
    }
  }
}

static __global__ void pad0_kernel(short* ph, short* pl, int ld, long long R, int c0, int c1) {
  int w = c1 - c0;
  long long total = R * w;
  long long i = (long long)blockIdx.x * blockDim.x + threadIdx.x;
  long long st = (long long)gridDim.x * blockDim.x;
  for (; i < total; i += st) {
    long long r = i / w; int c = c0 + (int)(i - r * w);
    ph[r * ld + c] = 0;
    pl[r * ld + c] = 0;
  }
}

// L1 tap finalize: o = a*Trec + b*D; write rm planes (Tcat slot) + tr planes (TTa)
static __global__ void cvt_dual_m(const float* __restrict__ Trec,
                                  const float* Xrm,
                                  const short* Dh, const short* Dl,
                                  short* __restrict__ rmh, short* __restrict__ rml,
                                  short* __restrict__ th, short* __restrict__ tl,
                                  long long GN, float a, float b) {
  long long total = GN * 6;
  long long i = (long long)blockIdx.x * blockDim.x + threadIdx.x;
  long long st = (long long)gridDim.x * blockDim.x;
  for (; i < total; i += st) {
    long long r = i / 6; int c = (int)(i - r * 6);
    float d = 0.f;
    if (Xrm) d = Xrm[i];
    else if (Dh) d = pget(Dh, Dl, r * 64 + c);
    float o = a * Trec[i] + b * d;
    pput(rmh, rml, r * 64 + c, o);
    pput(th, tl, (long long)c * GN + r, o);
  }
}

// ---------------- MFMA split-bf16 GEMM ----------------
// acc = A(MxK) @ BT(NcxK)^T.  M,Nc multiples of 128, K%32==0.
// mode 2: atomicAdd(C, alpha*acc)
// mode 3: planes out: o = alpha*acc + beta*planeD; optional transposed plane out (Th/Tl)
// mode 4: planes out: o = relu(acc + bias[R]); aux: atomicAdd sq[col] += o^2
// mode 5: planes out: o = (R==C)?0:exp(-(sq_r+sq_c-2*acc)); aux: atomicAdd deg[row] += o
static __global__ __launch_bounds__(256) void gemm_mf(
    const short* __restrict__ Ah, const short* __restrict__ Al, int lda, long long sA,
    const short* __restrict__ Bh, const short* __restrict__ Bl, int ldb, long long sB,
    const short* Dh, const short* Dl, int ldd, long long sD,
    float* C, short* Ch, short* Cl, int ldc, long long sC,
    short* Th, short* Tl, long long ldt,
    int M, int K, int Nc, float alpha, float beta,
    int mode, const float* sqp, long long sSq, float* aux,
    int ksplit, const float* __restrict__ bias) {
  int bz = blockIdx.z;
  int zb = bz / ksplit, zk = bz - zb * ksplit;
  Ah += (long long)zb * sA; Al += (long long)zb * sA;
  Bh += (long long)zb * sB; Bl += (long long)zb * sB;
  if (C) C += (long long)zb * sC;
  if (Ch) { Ch += (long long)zb * sC; Cl += (long long)zb * sC; }
  if (Dh) { Dh += (long long)zb * sD; Dl += (long long)zb * sD; }
  const float* sqb = sqp ? sqp + (long long)zb * sSq : nullptr;
  float* auxb = aux ? aux + (long long)zb * sSq : nullptr;

  int k_begin = 0, k_end = K;
  if (ksplit > 1) {
    int kslice = (((K / ksplit) + 31) >> 5) << 5;
    k_begin = zk * kslice;
    k_end = min(K, k_begin + kslice);
  }

  __shared__ __align__(16) short smem[4][4][128][8];  // 32 KB

  int row0 = blockIdx.y * 128, col0 = blockIdx.x * 128;
  int t = threadIdx.x;
  int w = t >> 6, lane = t & 63, g = lane >> 4, c = lane & 15;
  int wr = w >> 1, wc = w & 1;

  const short* gp = (w == 0) ? Ah : (w == 1) ? Al : (w == 2) ? Bh : Bl;
  long long gld = (w < 2) ? lda : ldb;
  long long grow0 = (w < 2) ? row0 : col0;
  short* lbase = &smem[w][0][0][0];

  f32x4 acc[4][4];
#pragma unroll
  for (int i = 0; i < 4; ++i)
#pragma unroll
    for (int j = 0; j < 4; ++j) {
      acc[i][j][0] = 0.f; acc[i][j][1] = 0.f; acc[i][j][2] = 0.f; acc[i][j][3] = 0.f;
    }

  for (int k0 = k_begin; k0 < k_end; k0 += 32) {
#pragma unroll
    for (int q = 0; q < 8; ++q) {
      int idx = q * 64 + lane;
      const short* src = gp + (grow0 + (idx & 127)) * gld + k0 + (idx >> 7) * 8;
      GLOAD16(src, lbase + idx * 8);
    }
    __syncthreads();
    s16x8 afH[4], afL[4], bfH[4], bfL[4];
#pragma unroll
    for (int mi = 0; mi < 4; ++mi) {
      int row = wr * 64 + mi * 16 + c;
      afH[mi] = *reinterpret_cast<const s16x8*>(&smem[0][g][row][0]);
      afL[mi] = *reinterpret_cast<const s16x8*>(&smem[1][g][row][0]);
    }
#pragma unroll
    for (int ni = 0; ni < 4; ++ni) {
      int row = wc * 64 + ni * 16 + c;
      bfH[ni] = *reinterpret_cast<const s16x8*>(&smem[2][g][row][0]);
      bfL[ni] = *reinterpret_cast<const s16x8*>(&smem[3][g][row][0]);
    }
#pragma unroll
    for (int mi = 0; mi < 4; ++mi)
#pragma unroll
      for (int ni = 0; ni < 4; ++ni) {
        acc[mi][ni] = __builtin_amdgcn_mfma_f32_16x16x32_bf16(afH[mi], bfH[ni], acc[mi][ni], 0, 0, 0);
        acc[mi][ni] = __builtin_amdgcn_mfma_f32_16x16x32_bf16(afH[mi], bfL[ni], acc[mi][ni], 0, 0, 0);
        acc[mi][ni] = __builtin_amdgcn_mfma_f32_16x16x32_bf16(afL[mi], bfH[ni], acc[mi][ni], 0, 0, 0);
      }
    __syncthreads();
  }

  float rs[4][4];   // mode 5 row-sums
  float sqa[4];     // mode 4 per-ni col sums
#pragma unroll
  for (int i = 0; i < 4; ++i) { sqa[i] = 0.f;
#pragma unroll
    for (int j = 0; j < 4; ++j) rs[i][j] = 0.f; }

#pragma unroll
  for (int mi = 0; mi < 4; ++mi) {
#pragma unroll
    for (int ni = 0; ni < 4; ++ni) {
      float o4[4];
#pragma unroll
      for (int r = 0; r < 4; ++r) {
        int R = row0 + wr * 64 + mi * 16 + g * 4 + r;
        int Cc2 = col0 + wc * 64 + ni * 16 + c;
        float v = acc[mi][ni][r];
        float o = 0.f;
        if (R < M && Cc2 < Nc) {
          long long idx = (long long)R * ldc + Cc2;
          if (mode == 5) {
            float d2 = sqb[R] + sqb[Cc2] - 2.f * v;
            o = (R == Cc2) ? 0.f : expf(-d2);
            pput(Ch, Cl, idx, o);
            rs[mi][r] += o;
          } else if (mode == 4) {
            o = fmaxf(v + bias[R], 0.f);
            pput(Ch, Cl, idx, o);
            sqa[ni] += o * o;
          } else if (mode == 2) {
            atomicAdd(&C[idx], alpha * v);
          } else {  // mode 3
            o = alpha * v;
            if (Dh) o += beta * pget(Dh, Dl, (long long)R * ldd + Cc2);
            pput(Ch, Cl, idx, o);
          }
        }
        o4[r] = o;
      }
      if (mode == 3 && Th) {
        int R0 = row0 + wr * 64 + mi * 16 + g * 4;
        int Cc2 = col0 + wc * 64 + ni * 16 + c;
        if (R0 < M && Cc2 < Nc) {
          long long base = (long long)Cc2 * ldt + (long long)zb * M + R0;
          s16x4 hv, lv;
#pragma unroll
          for (int r = 0; r < 4; ++r) {
            unsigned short h = f2bf(o4[r]);
            hv[r] = (short)h;
            lv[r] = (short)f2bf(o4[r] - bf2f(h));
          }
          *reinterpret_cast<s16x4*>(Th + base) = hv;
          *reinterpret_cast<s16x4*>(Tl + base) = lv;
        }
      }
    }
  }

  if (mode == 5 && auxb) {
#pragma unroll
    for (int mi = 0; mi < 4; ++mi)
#pragma unroll
      for (int r = 0; r < 4; ++r) {
        float s = rs[mi][r];
        s += __shfl_xor(s, 1);
        s += __shfl_xor(s, 2);
        s += __shfl_xor(s, 4);
        s += __shfl_xor(s, 8);
        if (c == 0) {
          int R = row0 + wr * 64 + mi * 16 + g * 4 + r;
          if (R < M) atomicAdd(&auxb[R], s);
        }
      }
  } else if (mode == 4 && aux) {
#pragma unroll
    for (int ni = 0; ni < 4; ++ni) {
      int Cc2 = col0 + wc * 64 + ni * 16 + c;
      if (Cc2 < Nc) atomicAdd(&aux[Cc2], sqa[ni]);
    }
  }
}

// ---------------- skinny GEMM (L1 recurrence, Nc=6) ----------------
static __global__ __launch_bounds__(256) void gemm_skinny(
    const short* __restrict__ Ah, const short* __restrict__ Al, int lda, long long sA,
    const short* __restrict__ Bh, const short* __restrict__ Bl, long long ldb, long long sB,
    float* C, int ldc, long long sC,
    int M, int K, int Nc, int ksplit) {
  int bz = blockIdx.z;
  int zb = bz / ksplit, zk = bz - zb * ksplit;
  Ah += (long long)zb * sA; Al += (long long)zb * sA;
  Bh += (long long)zb * sB; Bl += (long long)zb * sB;
  C += (long long)zb * sC;
  int kslice = (((K / ksplit) + 31) >> 5) << 5;
  int k_begin = zk * kslice, k_end = min(K, k_begin + kslice);
  int nt = (k_end > k_begin) ? (k_end - k_begin) >> 5 : 0;

  __shared__ __align__(16) short sm[2][4][128][8];

  int t = threadIdx.x, w = t >> 6, lane = t & 63, g = lane >> 4, c = lane & 15;
  int row0 = blockIdx.y * 128;

  f32x4 acc[2];
#pragma unroll
  for (int f = 0; f < 2; ++f) { acc[f][0] = 0.f; acc[f][1] = 0.f; acc[f][2] = 0.f; acc[f][3] = 0.f; }

  for (int tt = 0; tt < nt; ++tt) {
    int k0 = k_begin + tt * 32;
#pragma unroll
    for (int q = 0; q < 4; ++q) {
      int idx = q * 256 + t;
      int plane = idx >> 9, rem = idx & 511, kb = rem >> 7, row = rem & 127;
      const short* src = (plane ? Al : Ah) + (long long)(row0 + row) * lda + k0 + kb * 8;
      GLOAD16(src, &sm[0][0][0][0] + idx * 8);
    }
    __syncthreads();
    s16x8 bh = *reinterpret_cast<const s16x8*>(Bh + (long long)c * ldb + k0 + g * 8);
    s16x8 bl = *reinterpret_cast<const s16x8*>(Bl + (long long)c * ldb + k0 + g * 8);
    s16x8 aH0 = *reinterpret_cast<const s16x8*>(&sm[0][g][w * 32 + c][0]);
    s16x8 aH1 = *reinterpret_cast<const s16x8*>(&sm[0][g][w * 32 + 16 + c][0]);
    s16x8 aL0 = *reinterpret_cast<const s16x8*>(&sm[1][g][w * 32 + c][0]);
    s16x8 aL1 = *reinterpret_cast<const s16x8*>(&sm[1][g][w * 32 + 16 + c][0]);
    acc[0] = __builtin_amdgcn_mfma_f32_16x16x32_bf16(aH0, bh, acc[0], 0, 0, 0);
    acc[0] = __builtin_amdgcn_mfma_f32_16x16x32_bf16(aH0, bl, acc[0], 0, 0, 0);
    acc[0] = __builtin_amdgcn_mfma_f32_16x16x32_bf16(aL0, bh, acc[0], 0, 0, 0);
    acc[1] = __builtin_amdgcn_mfma_f32_16x16x32_bf16(aH1, bh, acc[1], 0, 0, 0);
    acc[1] = __builtin_amdgcn_mfma_f32_16x16x32_bf16(aH1, bl, acc[1], 0, 0, 0);
    acc[1] = __builtin_amdgcn_mfma_f32_16x16x32_bf16(aL1, bh, acc[1], 0, 0, 0);
    __syncthreads();
  }
#pragma unroll
  for (int f = 0; f < 2; ++f)
#pragma unroll
    for (int r = 0; r < 4; ++r) {
      int R = row0 + w * 32 + f * 16 + g * 4 + r;
      if (c < Nc && R < M) atomicAdd(&C[(long long)R * ldc + c], acc[f][r]);
    }
}

// ---------------- reductions / pool / FC ----------------

static __global__ void sumsq_kernel(const float* __restrict__ src, long long n, float* out) {
  float s = 0.f;
  long long i = (long long)blockIdx.x * blockDim.x + threadIdx.x;
  long long st = (long long)gridDim.x * blockDim.x;
  for (; i < n; i += st) { float v = src[i]; s += v * v; }
  __shared__ float red[256];
  red[threadIdx.x] = s;
  __syncthreads();
  for (int stp = 128; stp > 0; stp >>= 1) {
    if (threadIdx.x < stp) red[threadIdx.x] += red[threadIdx.x + stp];
    __syncthreads();
  }
  if (threadIdx.x == 0) atomicAdd(out, red[0]);
}

static __global__ void maxpool_p(const short* __restrict__ Hh, const short* __restrict__ Hl,
                                 float* __restrict__ g, int N, long long GN, int F, int Gb) {
  int wid = (int)(((long long)blockIdx.x * blockDim.x + threadIdx.x) >> 6);
  int lane = threadIdx.x & 63;
  if (wid >= Gb * F) return;
  int b = wid / F, f = wid - b * F;
  long long base = (long long)f * GN + (long long)b * N;
  float m = -INFINITY;
  for (int n = lane; n < N; n += 64) m = fmaxf(m, pget(Hh, Hl, base + n));
  for (int off = 32; off; off >>= 1) m = fmaxf(m, __shfl_down(m, off));
  if (lane == 0) g[(long long)b * F + f] = m;
}

static __global__ void fc_kernel(const float* __restrict__ in, const float* __restrict__ W,
                                 const float* __restrict__ bias, float* out,
                                 int Bc, int K, int J, int do_relu) {
  int gtid = blockIdx.x * blockDim.x + threadIdx.x;
  int wid = gtid >> 6;
  int lane = gtid & 63;
  if (wid >= Bc * J) return;
  int b = wid / J, j = wid - b * J;
  const float* ib = in + (long long)b * K;
  const float* wj = W + (long long)j * K;
  float s = 0.f;
  for (int k = lane; k < K; k += 64) s += ib[k] * wj[k];
  for (int off = 32; off > 0; off >>= 1) s += __shfl_down(s, off);
  if (lane == 0) {
    s += bias[j];
    out[wid] = do_relu ? fmaxf(s, 0.f) : s;
  }
}

static __global__ void finalize_kernel(const float* scal, float* out_regs) {
  if (threadIdx.x == 0 && blockIdx.x == 0) {
    float r1 = sqrtf(scal[0]), r2 = sqrtf(scal[1]), r3 = sqrtf(scal[2]);
    float nw = sqrtf(scal[3]), nb = sqrtf(scal[4]);
    out_regs[0] = r1; out_regs[1] = r2; out_regs[2] = r3;
    out_regs[3] = nw; out_regs[4] = nb;
    out_regs[5] = nw; out_regs[6] = nb;
    out_regs[7] = nw; out_regs[8] = nb;
  }
}

// ---------------- host orchestration ----------------

struct Ptrs {
  short *Lh, *Ll, *Tch, *Tcl, *TTah, *TTbh, *TTal, *TTbl, *Xgh, *Xgl;
  short *HTh, *HTl;
  short *W1h, *W1l, *W2h, *W2l, *W3h, *W3l;
  float *Trec, *Mm1, *Mm2, *Mm3, *sq, *dinv, *deg, *gb, *o1, *o2, *scal;
};

extern "C" void kernel_launch(void* const* d_in, const int* in_sizes, int n_in,
                              void* d_out, int out_size, void* d_ws, size_t ws_size,
                              hipStream_t stream) {
  const float* x   = (const float*)d_in[0];
  const float* w1  = (const float*)d_in[4];
  const float* b1  = (const float*)d_in[5];
  const float* w2  = (const float*)d_in[6];
  const float* b2  = (const float*)d_in[7];
  const float* w3  = (const float*)d_in[8];
  const float* b3  = (const float*)d_in[9];
  const float* fw1 = (const float*)d_in[10];
  const float* fb1 = (const float*)d_in[11];
  const float* fw2 = (const float*)d_in[12];
  const float* fb2 = (const float*)d_in[13];
  const float* fw3 = (const float*)d_in[14];
  const float* fb3 = (const float*)d_in[15];
  float* out = (float*)d_out;

  float* ws = (float*)d_ws;
  const long long NN = (long long)N_ * N_;

  Ptrs p;
  auto layout = [&](int G) -> unsigned long long {
    long long off = 0;  // floats
    auto aF = [&](long long n) { float* q = ws + off; off += (n + 7) & ~7LL; return q; };
    auto aS = [&](long long n) { short* q = (short*)(ws + off); off += (((n + 1) >> 1) + 7) & ~7LL; return q; };
    long long GN = (long long)G * N_;
    p.Lh = aS(G * NN); p.Ll = aS(G * NN);
    p.Tch = aS(GN * 1536); p.Tcl = aS(GN * 1536);
    p.TTah = aS(GN * 512); p.TTbh = aS(GN * 512);  // adjacent: LHh alias spans both
    p.TTal = aS(GN * 512); p.TTbl = aS(GN * 512);  // adjacent: LHl alias spans both
    p.Xgh = aS(GN * 32); p.Xgl = aS(GN * 32);
    p.HTh = aS(GN * 1024); p.HTl = aS(GN * 1024);
    p.W1h = aS(128 * 64); p.W1l = aS(128 * 64);
    p.W2h = aS(512 * 640); p.W2l = aS(512 * 640);
    p.W3h = aS(1024 * 1536); p.W3l = aS(1024 * 1536);
    p.Trec = aF(GN * 6 + 64);
    p.Mm1 = aF(128 * 128); p.Mm2 = aF(512 * 512); p.Mm3 = aF(1024 * 1024);
    p.sq = aF(GN); p.dinv = aF(GN); p.deg = aF(GN);
    p.gb = aF(B_ * 1024); p.o1 = aF(B_ * 512); p.o2 = aF(B_ * 128);
    p.scal = aF(16);
    return (unsigned long long)off * 4ULL;
  };
  int G = 16;
  while (G > 1 && layout(G) > ws_size) G >>= 1;
  if (layout(G) > ws_size) return;
  layout(G);
  short* LHh = p.TTah;  // spans TTah+TTbh = GN*1024
  short* LHl = p.TTal;

  const long long GN = (long long)G * N_;
  auto blk1d = [](long long n) { return (int)(((n + 255) / 256 < 4096) ? (n + 255) / 256 : 4096); };

  int skSK = 64 / G; if (skSK < 1) skSK = 1;
  int mm1SK = (int)(GN / 32);
  int mm2SK = 32, mm3SK = 8;

  // ---- W plane conversions (Fout x Kpad) ----
  cvt_tr_kernel<<<dim3(4, 1, 6), dim3(32, 8), 0, stream>>>(
      w1, 128, 6LL * 128, p.W1h, p.W1l, 64, 6, 6, 128);
  pad0_kernel<<<blk1d(128LL * 28), 256, 0, stream>>>(p.W1h, p.W1l, 64, 128, 36, 64);
  cvt_tr_kernel<<<dim3(16, 4, 5), dim3(32, 8), 0, stream>>>(
      w2, 512, 128LL * 512, p.W2h, p.W2l, 640, 128, 128, 512);
  cvt_tr_kernel<<<dim3(32, 16, 3), dim3(32, 8), 0, stream>>>(
      w3, 1024, 512LL * 1024, p.W3h, p.W3l, 1536, 512, 512, 1024);
  pad0_kernel<<<blk1d(GN * 26), 256, 0, stream>>>(p.Xgh, p.Xgl, 32, GN, 6, 32);

  zerof_kernel<<<1, 256, 0, stream>>>(p.scal, 16);
  zerof_kernel<<<64, 256, 0, stream>>>(p.Mm1, 128LL * 128);
  zerof_kernel<<<256, 256, 0, stream>>>(p.Mm2, 512LL * 512);
  zerof_kernel<<<1024, 256, 0, stream>>>(p.Mm3, 1024LL * 1024);

  auto do_layer = [&](const float* Xrm, int Fin, int taps, int Fout, const float* bias,
                      const short* Wh, const short* Wl, int Kpad, int mmSK, float* Mm) {
    // ---- prep: Tcat slot0 (+ sq + T0^T) ----
    if (Xrm) {
      rowsq_small<<<blk1d(GN), 256, 0, stream>>>(Xrm, p.sq, 6, GN);
      cvt_rm_kernel<<<blk1d(GN * 6), 256, 0, stream>>>(Xrm, 6, p.Tch, p.Tcl, 64, GN, 6);
      pad0_kernel<<<blk1d(GN * 28), 256, 0, stream>>>(p.Tch, p.Tcl, 64, GN, 36, 64);
      cvt_rm_kernel<<<blk1d(GN * 6), 256, 0, stream>>>(Xrm, 6, p.Xgh, p.Xgl, 32, GN, 6);
      cvt_tr_kernel<<<dim3(1, 64, G), dim3(32, 8), 0, stream>>>(
          Xrm, 6, (long long)N_ * 6, p.TTah, p.TTal, GN, N_, N_, 6);
    } else {
      // sq already filled by previous proj; Tcat slot0 from HT
      tr_pp_kernel<<<dim3((int)(GN / 32), Fin / 32), dim3(32, 8), 0, stream>>>(
          p.HTh, p.HTl, GN, p.Tch, p.Tcl, Kpad, Fin, GN);
    }
    // ---- graph (mode 5) -> L planes + deg atomics ----
    zerof_kernel<<<blk1d(GN), 256, 0, stream>>>(p.deg, GN);
    const short* Gh = Xrm ? p.Xgh : p.Tch;
    const short* Gl = Xrm ? p.Xgl : p.Tcl;
    int glda = Xrm ? 32 : Kpad;
    int GK = Xrm ? 32 : Fin;
    gemm_mf<<<dim3(16, 16, G), 256, 0, stream>>>(
        Gh, Gl, glda, (long long)N_ * glda, Gh, Gl, glda, (long long)N_ * glda,
        nullptr, nullptr, 0, 0,
        nullptr, p.Lh, p.Ll, N_, NN,
        nullptr, nullptr, 0,
        N_, GK, N_, 1.f, 0.f, 5, p.sq, N_, p.deg, 1, nullptr);
    dinv_from_deg<<<blk1d(GN), 256, 0, stream>>>(p.deg, p.dinv, GN);
    scaleL_p<<<4096, 256, 0, stream>>>(p.Lh, p.Ll, p.dinv, G * NN);
    // ---- chebyshev recurrence ----
    for (int k = 1; k < taps; ++k) {
      if (Fin == 6) {
        zerof_kernel<<<blk1d(GN * 6), 256, 0, stream>>>(p.Trec, GN * 6);
        gemm_skinny<<<dim3(1, 16, G * skSK), 256, 0, stream>>>(
            p.Lh, p.Ll, N_, NN, p.TTah, p.TTal, GN, N_,
            p.Trec, 6, (long long)N_ * 6, N_, N_, 6, skSK);
        cvt_dual_m<<<blk1d(GN * 6), 256, 0, stream>>>(
            p.Trec, (k == 2) ? Xrm : nullptr,
            (k > 2) ? p.Tch + (long long)(k - 2) * 6 : nullptr,
            (k > 2) ? p.Tcl + (long long)(k - 2) * 6 : nullptr,
            p.Tch + (long long)k * 6, p.Tcl + (long long)k * 6,
            p.TTah, p.TTal, GN, (k == 1) ? 1.f : 2.f, (k == 1) ? 0.f : -1.f);
      } else {
        const short* Bh_ = (k == 1) ? p.HTh : (((k - 2) & 1) ? p.TTbh : p.TTah);
        const short* Bl_ = (k == 1) ? p.HTl : (((k - 2) & 1) ? p.TTbl : p.TTal);
        short* Th_ = ((k - 1) & 1) ? p.TTbh : p.TTah;
        short* Tl_ = ((k - 1) & 1) ? p.TTbl : p.TTal;
        const short* Dh_ = (k >= 2) ? p.Tch + (long long)(k - 2) * Fin : nullptr;
        const short* Dl_ = (k >= 2) ? p.Tcl + (long long)(k - 2) * Fin : nullptr;
        gemm_mf<<<dim3(Fin / 128, 16, G), 256, 0, stream>>>(
            p.Lh, p.Ll, N_, NN, Bh_, Bl_, (int)GN, N_,
            Dh_, Dl_, Kpad, (long long)N_ * Kpad,
            nullptr, p.Tch + (long long)k * Fin, p.Tcl + (long long)k * Fin, Kpad, (long long)N_ * Kpad,
            Th_, Tl_, GN,
            N_, N_, Fin, (k == 1) ? 1.f : 2.f, (k == 1) ? 0.f : -1.f,
            3, nullptr, 0, nullptr, 1, nullptr);
      }
    }
    // ---- projection (mode 4): HT planes = relu(Wcat^T @ Tcat^T + bias), sq atomics ----
    zerof_kernel<<<blk1d(GN), 256, 0, stream>>>(p.sq, GN);
    gemm_mf<<<dim3((int)(GN / 128), Fout / 128, 1), 256, 0, stream>>>(
        Wh, Wl, Kpad, 0, p.Tch, p.Tcl, Kpad, 0,
        nullptr, nullptr, 0, 0,
        nullptr, p.HTh, p.HTl, (int)GN, 0,
        nullptr, nullptr, 0,
        Fout, Kpad, (int)GN, 1.f, 0.f, 4, nullptr, 0, p.sq, 1, bias);
    // ---- LHT = H^T L + H^T (mode 3 -> LH planes over TT region) ----
    gemm_mf<<<dim3(16, Fout / 128, G), 256, 0, stream>>>(
        p.HTh, p.HTl, (int)GN, N_, p.Lh, p.Ll, N_, NN,
        p.HTh, p.HTl, (int)GN, N_,
        nullptr, LHh, LHl, (int)GN, N_,
        nullptr, nullptr, 0,
        Fout, N_, N_, 1.f, 1.f, 3, nullptr, 0, nullptr, 1, nullptr);
    // ---- Mm += H^T (L+I) H (mode 2, split-K) ----
    gemm_mf<<<dim3(Fout / 128, Fout / 128, mmSK), 256, 0, stream>>>(
        p.HTh, p.HTl, (int)GN, 0, LHh, LHl, (int)GN, 0,
        nullptr, nullptr, 0, 0,
        Mm, nullptr, nullptr, Fout, 0,
        nullptr, nullptr, 0,
        Fout, (int)GN, Fout, 1.f, 0.f, 2, nullptr, 0, nullptr, mmSK, nullptr);
  };

  for (int c = 0; c < B_ / G; ++c) {
    const float* Xc = x + (long long)c * GN * 6;
    do_layer(Xc, 6, 6, 128, b1, p.W1h, p.W1l, 64, mm1SK, p.Mm1);
    do_layer(nullptr, 128, 5, 512, b2, p.W2h, p.W2l, 640, mm2SK, p.Mm2);
    do_layer(nullptr, 512, 3, 1024, b3, p.W3h, p.W3l, 1536, mm3SK, p.Mm3);
    maxpool_p<<<(G * 1024 * 64 + 255) / 256, 256, 0, stream>>>(
        p.HTh, p.HTl, p.gb + (long long)c * G * 1024, N_, GN, 1024, G);
  }

  sumsq_kernel<<<64, 256, 0, stream>>>(p.Mm1, 128LL * 128, p.scal + 0);
  sumsq_kernel<<<256, 256, 0, stream>>>(p.Mm2, 512LL * 512, p.scal + 1);
  sumsq_kernel<<<256, 256, 0, stream>>>(p.Mm3, 1024LL * 1024, p.scal + 2);

  fc_kernel<<<(B_ * 512 * 64 + 255) / 256, 256, 0, stream>>>(p.gb, fw1, fb1, p.o1, B_, 1024, 512, 1);
  fc_kernel<<<(B_ * 128 * 64 + 255) / 256, 256, 0, stream>>>(p.o1, fw2, fb2, p.o2, B_, 512, 128, 1);
  fc_kernel<<<(B_ * 10 * 64 + 255) / 256, 256, 0, stream>>>(p.o2, fw3, fb3, out, B_, 128, 10, 0);

  sumsq_kernel<<<256, 256, 0, stream>>>(fw1, 512LL * 1024, p.scal + 3);
  sumsq_kernel<<<1, 256, 0, stream>>>(fb1, 512LL, p.scal + 4);
  finalize_kernel<<<1, 64, 0, stream>>>(p.scal, out + 160);
}

// Round 9
// 6177.202 us; speedup vs baseline: 1.8755x; 1.8755x over previous
//
#include <hip/hip_runtime.h>

#define B_ 16
#define N_ 2048

typedef __attribute__((ext_vector_type(8))) short s16x8;
typedef __attribute__((ext_vector_type(4))) float f32x4;

#define GLOAD16(gp, lp) __builtin_amdgcn_global_load_lds( \
    (const __attribute__((address_space(1))) void*)(gp),  \
    (__attribute__((address_space(3))) void*)(lp), 16, 0, 0)

__device__ inline unsigned short f2bf(float f) {
  unsigned u = __float_as_uint(f);
  u += 0x7FFFu + ((u >> 16) & 1u);
  return (unsigned short)(u >> 16);
}
__device__ inline float bf2f(unsigned short h) {
  return __uint_as_float(((unsigned)h) << 16);
}
__device__ inline float pget(const short* __restrict__ ph, const short* __restrict__ pl, long long i) {
  return bf2f((unsigned short)ph[i]) + bf2f((unsigned short)pl[i]);
}
__device__ inline void pput(short* __restrict__ ph, short* __restrict__ pl, long long i, float v) {
  unsigned short h = f2bf(v);
  ph[i] = (short)h;
  pl[i] = (short)f2bf(v - bf2f(h));
}

// ---------------- utility kernels ----------------

static __global__ void zerof_kernel(float* p, long long n) {
  long long i = (long long)blockIdx.x * blockDim.x + threadIdx.x;
  long long st = (long long)gridDim.x * blockDim.x;
  for (; i < n; i += st) p[i] = 0.f;
}

static __global__ void rowsq_small(const float* __restrict__ X, float* __restrict__ sq,
                                   int F, long long R) {
  long long i = (long long)blockIdx.x * blockDim.x + threadIdx.x;
  if (i >= R) return;
  const float* xr = X + i * F;
  float s = 0.f;
  for (int f = 0; f < F; ++f) s += xr[f] * xr[f];
  sq[i] = s;
}

static __global__ void dinv_from_deg(const float* __restrict__ deg, float* __restrict__ dinv, long long n) {
  long long i = (long long)blockIdx.x * blockDim.x + threadIdx.x;
  if (i >= n) return;
  float d = deg[i];
  dinv[i] = (d > 0.f) ? rsqrtf(d) : 0.f;
}

// in-place: L <- -L * dinv_r * dinv_j  (split planes), N_=2048
static __global__ void scaleL_p(short* Lh, short* Ll, const float* __restrict__ dinv, long long total) {
  long long i = (long long)blockIdx.x * blockDim.x + threadIdx.x;
  long long st = (long long)gridDim.x * blockDim.x;
  for (; i < total; i += st) {
    int j = (int)(i & (N_ - 1));
    long long bn = i >> 11;
    float v = pget(Lh, Ll, i);
    v = -v * dinv[bn] * dinv[((bn >> 11) << 11) + j];
    pput(Lh, Ll, i, v);
  }
}

// f32 row-major -> planes
static __global__ void cvt_rm_kernel(const float* __restrict__ src, int lds,
                                     short* __restrict__ dh, short* __restrict__ dl,
                                     int ldd, long long R, int Cc) {
  long long total = R * Cc;
  long long i = (long long)blockIdx.x * blockDim.x + threadIdx.x;
  long long st = (long long)gridDim.x * blockDim.x;
  for (; i < total; i += st) {
    long long r = i / Cc; int c = (int)(i - r * Cc);
    pput(dh, dl, r * ldd + c, src[r * lds + c]);
  }
}

// f32 -> transposed planes (z-batched)
static __global__ void cvt_tr_kernel(const float* __restrict__ src, int lds, long long sS,
                                     short* __restrict__ dh, short* __restrict__ dl,
                                     long long ldd, long long sD, int R, int Cc) {
  int z = blockIdx.z;
  src += (long long)z * sS;
  dh += (long long)z * sD;
  dl += (long long)z * sD;
  __shared__ float tile[32][33];
  int r0 = blockIdx.y * 32, c0 = blockIdx.x * 32;
  int tx = threadIdx.x, ty = threadIdx.y;
#pragma unroll
  for (int i = 0; i < 32; i += 8) {
    int r = r0 + ty + i, cx = c0 + tx;
    tile[ty + i][tx] = (r < R && cx < Cc) ? src[(long long)r * lds + cx] : 0.f;
  }
  __syncthreads();
#pragma unroll
  for (int i = 0; i < 32; i += 8) {
    int cr = c0 + ty + i, rx = r0 + tx;
    if (cr < Cc && rx < R) pput(dh, dl, (long long)cr * ldd + rx, tile[tx][ty + i]);
  }
}

// plane->plane transpose
static __global__ void tr_pp_kernel(const short* __restrict__ sh, const short* __restrict__ sl,
                                    long long lds, short* __restrict__ dh, short* __restrict__ dl,
                                    int ldd, int R, long long Cc) {
  __shared__ short th[32][33], tl[32][33];
  int r0 = blockIdx.y * 32;
  long long c0 = (long long)blockIdx.x * 32;
  int tx = threadIdx.x, ty = threadIdx.y;
#pragma unroll
  for (int i = 0; i < 32; i += 8) {
    int r = r0 + ty + i;
    long long cx = c0 + tx;
    short vh = 0, vl = 0;
    if (r < R && cx < Cc) { vh = sh[(long long)r * lds + cx]; vl = sl[(long long)r * lds + cx]; }
    th[ty + i][tx] = vh;
    tl[ty + i][tx] = vl;
  }
  __syncthreads();
#pragma unroll
  for (int i = 0; i < 32; i += 8) {
    long long cr = c0 + ty + i;
    int rx = r0 + tx;
    if (cr < Cc && rx < R) {
      dh[cr * ldd + rx] = th[tx][ty + i];
      dl[cr * ldd + rx] = tl[tx][ty + i];
    }
  }
}

static __global__ void pad0_kernel(short* ph, short* pl, int ld, long long R, int c0, int c1) {
  int w = c1 - c0;
  long long total = R * w;
  long long i = (long long)blockIdx.x * blockDim.x + threadIdx.x;
  long long st = (long long)gridDim.x * blockDim.x;
  for (; i < total; i += st) {
    long long r = i / w; int c = c0 + (int)(i - r * w);
    ph[r * ld + c] = 0;
    pl[r * ld + c] = 0;
  }
}

// recurrence finalize (Fin>=32): o = a*S - D; write rm planes (Tc slot) + tr planes (TT)
static __global__ void cvt_dual_d(const float* __restrict__ S, int lds_,
                                  const short* Dh, const short* Dl, int ldd,
                                  short* __restrict__ rh, short* __restrict__ rl, int ldr,
                                  short* __restrict__ th, short* __restrict__ tl, long long ldt,
                                  long long R, int Cc, float a) {
  __shared__ float tile[32][33];
  long long r0 = (long long)blockIdx.y * 32;
  int c0 = blockIdx.x * 32;
  int tx = threadIdx.x, ty = threadIdx.y;
#pragma unroll
  for (int i = 0; i < 32; i += 8) {
    long long r = r0 + ty + i;
    int cx = c0 + tx;
    float v = 0.f;
    if (r < R && cx < Cc) {
      v = a * S[r * lds_ + cx];
      if (Dh) v -= pget(Dh, Dl, r * ldd + cx);
      pput(rh, rl, r * ldr + cx, v);
    }
    tile[ty + i][tx] = v;
  }
  __syncthreads();
#pragma unroll
  for (int i = 0; i < 32; i += 8) {
    int cr = c0 + ty + i;
    long long rx = r0 + tx;
    if (cr < Cc && rx < R) pput(th, tl, (long long)cr * ldt + rx, tile[tx][ty + i]);
  }
}

// L1 tap finalize (Fin=6): o = a*Trec + b*D
static __global__ void cvt_dual_m(const float* __restrict__ Trec,
                                  const float* Xrm,
                                  const short* Dh, const short* Dl,
                                  short* __restrict__ rmh, short* __restrict__ rml,
                                  short* __restrict__ th, short* __restrict__ tl,
                                  long long GN, float a, float b) {
  long long total = GN * 6;
  long long i = (long long)blockIdx.x * blockDim.x + threadIdx.x;
  long long st = (long long)gridDim.x * blockDim.x;
  for (; i < total; i += st) {
    long long r = i / 6; int c = (int)(i - r * 6);
    float d = 0.f;
    if (Xrm) d = Xrm[i];
    else if (Dh) d = pget(Dh, Dl, r * 64 + c);
    float o = a * Trec[i] + b * d;
    pput(rmh, rml, r * 64 + c, o);
    pput(th, tl, (long long)c * GN + r, o);
  }
}

// ---------------- MFMA split-bf16 GEMM (coalesced staging) ----------------
// acc = A(MxK) @ BT(NcxK)^T.  M,Nc mult of 128, K mult of 32, lda/ldb mult of 8.
// BSINGLE: B has only hi plane (2 MFMAs per product).
// mode 2: atomicAdd(C, alpha*acc)
// mode 3: o = alpha*acc + beta*planeD -> Ch/Cl planes (single if Cl==null)
// mode 4: o = relu(acc + bias[R]) -> planes; aux: atomicAdd sq[col] += o^2
// mode 5: o = (R==C)?0:exp(-(sq_r+sq_c-2*acc)) -> planes; aux: atomicAdd deg[row] += o
template <int BSINGLE>
static __global__ __launch_bounds__(256) void gemm_mf(
    const short* __restrict__ Ah, const short* __restrict__ Al, int lda, long long sA,
    const short* __restrict__ Bh, const short* __restrict__ Bl, int ldb, long long sB,
    const short* Dh, const short* Dl, int ldd, long long sD,
    float* C, short* Ch, short* Cl, int ldc, long long sC,
    int M, int K, int Nc, float alpha, float beta,
    int mode, const float* sqp, long long sSq, float* aux,
    int ksplit, const float* __restrict__ bias) {
  int bz = blockIdx.z;
  int zb = bz / ksplit, zk = bz - zb * ksplit;
  Ah += (long long)zb * sA; Al += (long long)zb * sA;
  Bh += (long long)zb * sB;
  if (!BSINGLE) Bl += (long long)zb * sB;
  if (C) C += (long long)zb * sC;
  if (Ch) Ch += (long long)zb * sC;
  if (Cl) Cl += (long long)zb * sC;
  if (Dh) { Dh += (long long)zb * sD; Dl += (long long)zb * sD; }
  const float* sqb = sqp ? sqp + (long long)zb * sSq : nullptr;
  float* auxb = aux ? aux + (long long)zb * sSq : nullptr;

  int k_begin = 0, k_end = K;
  if (ksplit > 1) {
    int kslice = (((K / ksplit) + 31) >> 5) << 5;
    k_begin = zk * kslice;
    k_end = min(K, k_begin + kslice);
  }

  // per plane: [128 rows][32 shorts] row-major (64B rows)
  __shared__ __align__(16) short smem[4][128][32];  // 32 KB

  int row0 = blockIdx.y * 128, col0 = blockIdx.x * 128;
  int t = threadIdx.x;
  int w = t >> 6, lane = t & 63, g = lane >> 4, c = lane & 15;
  int wr = w >> 1, wc = w & 1;

  const short* gp = (w == 0) ? Ah : (w == 1) ? Al : (w == 2) ? Bh : (BSINGLE ? nullptr : Bl);
  long long gld = (w < 2) ? lda : ldb;
  long long grow0 = (w < 2) ? row0 : col0;
  short* lbase = &smem[w][0][0];

  f32x4 acc[4][4];
#pragma unroll
  for (int i = 0; i < 4; ++i)
#pragma unroll
    for (int j = 0; j < 4; ++j) {
      acc[i][j][0] = 0.f; acc[i][j][1] = 0.f; acc[i][j][2] = 0.f; acc[i][j][3] = 0.f;
    }

  for (int k0 = k_begin; k0 < k_end; k0 += 32) {
    if (gp) {
      // coalesced: lanes 0-3 cover one 64B row-segment; 16 rows per load
#pragma unroll
      for (int q = 0; q < 8; ++q) {
        int idx = q * 64 + lane;
        int row = idx >> 2, kc = idx & 3;
        const short* src = gp + (grow0 + row) * gld + k0 + kc * 8;
        GLOAD16(src, lbase + idx * 8);
      }
    }
    __syncthreads();
    s16x8 afH[4], afL[4], bfH[4], bfL[4];
#pragma unroll
    for (int mi = 0; mi < 4; ++mi) {
      int row = wr * 64 + mi * 16 + c;
      afH[mi] = *reinterpret_cast<const s16x8*>(&smem[0][row][g * 8]);
      afL[mi] = *reinterpret_cast<const s16x8*>(&smem[1][row][g * 8]);
    }
#pragma unroll
    for (int ni = 0; ni < 4; ++ni) {
      int row = wc * 64 + ni * 16 + c;
      bfH[ni] = *reinterpret_cast<const s16x8*>(&smem[2][row][g * 8]);
      if (!BSINGLE) bfL[ni] = *reinterpret_cast<const s16x8*>(&smem[3][row][g * 8]);
    }
#pragma unroll
    for (int mi = 0; mi < 4; ++mi)
#pragma unroll
      for (int ni = 0; ni < 4; ++ni) {
        acc[mi][ni] = __builtin_amdgcn_mfma_f32_16x16x32_bf16(afH[mi], bfH[ni], acc[mi][ni], 0, 0, 0);
        if (!BSINGLE)
          acc[mi][ni] = __builtin_amdgcn_mfma_f32_16x16x32_bf16(afH[mi], bfL[ni], acc[mi][ni], 0, 0, 0);
        acc[mi][ni] = __builtin_amdgcn_mfma_f32_16x16x32_bf16(afL[mi], bfH[ni], acc[mi][ni], 0, 0, 0);
      }
    __syncthreads();
  }

  float rs[4][4];
  float sqa[4];
#pragma unroll
  for (int i = 0; i < 4; ++i) { sqa[i] = 0.f;
#pragma unroll
    for (int j = 0; j < 4; ++j) rs[i][j] = 0.f; }

#pragma unroll
  for (int mi = 0; mi < 4; ++mi) {
#pragma unroll
    for (int ni = 0; ni < 4; ++ni) {
#pragma unroll
      for (int r = 0; r < 4; ++r) {
        int R = row0 + wr * 64 + mi * 16 + g * 4 + r;
        int Cc2 = col0 + wc * 64 + ni * 16 + c;
        if (R < M && Cc2 < Nc) {
          float v = acc[mi][ni][r];
          long long idx = (long long)R * ldc + Cc2;
          if (mode == 5) {
            float d2 = sqb[R] + sqb[Cc2] - 2.f * v;
            float o = (R == Cc2) ? 0.f : expf(-d2);
            pput(Ch, Cl, idx, o);
            rs[mi][r] += o;
          } else if (mode == 4) {
            float o = fmaxf(v + bias[R], 0.f);
            pput(Ch, Cl, idx, o);
            sqa[ni] += o * o;
          } else if (mode == 2) {
            atomicAdd(&C[idx], alpha * v);
          } else {  // mode 3
            float o = alpha * v;
            if (Dh) o += beta * pget(Dh, Dl, (long long)R * ldd + Cc2);
            if (Cl) pput(Ch, Cl, idx, o);
            else Ch[idx] = (short)f2bf(o);
          }
        }
      }
    }
  }

  if (mode == 5 && auxb) {
#pragma unroll
    for (int mi = 0; mi < 4; ++mi)
#pragma unroll
      for (int r = 0; r < 4; ++r) {
        float s = rs[mi][r];
        s += __shfl_xor(s, 1);
        s += __shfl_xor(s, 2);
        s += __shfl_xor(s, 4);
        s += __shfl_xor(s, 8);
        if (c == 0) {
          int R = row0 + wr * 64 + mi * 16 + g * 4 + r;
          if (R < M) atomicAdd(&auxb[R], s);
        }
      }
  } else if (mode == 4 && aux) {
#pragma unroll
    for (int ni = 0; ni < 4; ++ni) {
      int Cc2 = col0 + wc * 64 + ni * 16 + c;
      if (Cc2 < Nc) atomicAdd(&aux[Cc2], sqa[ni]);
    }
  }
}

// ---------------- skinny GEMM (L1 recurrence, Nc=6) ----------------
static __global__ __launch_bounds__(256) void gemm_skinny(
    const short* __restrict__ Ah, const short* __restrict__ Al, int lda, long long sA,
    const short* __restrict__ Bh, const short* __restrict__ Bl, long long ldb, long long sB,
    float* C, int ldc, long long sC,
    int M, int K, int Nc, int ksplit) {
  int bz = blockIdx.z;
  int zb = bz / ksplit, zk = bz - zb * ksplit;
  Ah += (long long)zb * sA; Al += (long long)zb * sA;
  Bh += (long long)zb * sB; Bl += (long long)zb * sB;
  C += (long long)zb * sC;
  int kslice = (((K / ksplit) + 31) >> 5) << 5;
  int k_begin = zk * kslice, k_end = min(K, k_begin + kslice);
  int nt = (k_end > k_begin) ? (k_end - k_begin) >> 5 : 0;

  __shared__ __align__(16) short sm[2][128][32];

  int t = threadIdx.x, w = t >> 6, lane = t & 63, g = lane >> 4, c = lane & 15;
  int row0 = blockIdx.y * 128;

  f32x4 acc[2];
#pragma unroll
  for (int f = 0; f < 2; ++f) { acc[f][0] = 0.f; acc[f][1] = 0.f; acc[f][2] = 0.f; acc[f][3] = 0.f; }

  for (int tt = 0; tt < nt; ++tt) {
    int k0 = k_begin + tt * 32;
#pragma unroll
    for (int q = 0; q < 4; ++q) {
      int idx = q * 256 + t;
      int plane = idx >> 9, rem = idx & 511, row = rem >> 2, kc = rem & 3;
      const short* src = (plane ? Al : Ah) + (long long)(row0 + row) * lda + k0 + kc * 8;
      GLOAD16(src, &sm[0][0][0] + idx * 8);
    }
    __syncthreads();
    s16x8 bh = *reinterpret_cast<const s16x8*>(Bh + (long long)c * ldb + k0 + g * 8);
    s16x8 bl = *reinterpret_cast<const s16x8*>(Bl + (long long)c * ldb + k0 + g * 8);
    s16x8 aH0 = *reinterpret_cast<const s16x8*>(&sm[0][w * 32 + c][g * 8]);
    s16x8 aH1 = *reinterpret_cast<const s16x8*>(&sm[0][w * 32 + 16 + c][g * 8]);
    s16x8 aL0 = *reinterpret_cast<const s16x8*>(&sm[1][w * 32 + c][g * 8]);
    s16x8 aL1 = *reinterpret_cast<const s16x8*>(&sm[1][w * 32 + 16 + c][g * 8]);
    acc[0] = __builtin_amdgcn_mfma_f32_16x16x32_bf16(aH0, bh, acc[0], 0, 0, 0);
    acc[0] = __builtin_amdgcn_mfma_f32_16x16x32_bf16(aH0, bl, acc[0], 0, 0, 0);
    acc[0] = __builtin_amdgcn_mfma_f32_16x16x32_bf16(aL0, bh, acc[0], 0, 0, 0);
    acc[1] = __builtin_amdgcn_mfma_f32_16x16x32_bf16(aH1, bh, acc[1], 0, 0, 0);
    acc[1] = __builtin_amdgcn_mfma_f32_16x16x32_bf16(aH1, bl, acc[1], 0, 0, 0);
    acc[1] = __builtin_amdgcn_mfma_f32_16x16x32_bf16(aL1, bh, acc[1], 0, 0, 0);
    __syncthreads();
  }
#pragma unroll
  for (int f = 0; f < 2; ++f)
#pragma unroll
    for (int r = 0; r < 4; ++r) {
      int R = row0 + w * 32 + f * 16 + g * 4 + r;
      if (c < Nc && R < M) atomicAdd(&C[(long long)R * ldc + c], acc[f][r]);
    }
}

// ---------------- reductions / pool / FC ----------------

static __global__ void sumsq_kernel(const float* __restrict__ src, long long n, float* out) {
  float s = 0.f;
  long long i = (long long)blockIdx.x * blockDim.x + threadIdx.x;
  long long st = (long long)gridDim.x * blockDim.x;
  for (; i < n; i += st) { float v = src[i]; s += v * v; }
  __shared__ float red[256];
  red[threadIdx.x] = s;
  __syncthreads();
  for (int stp = 128; stp > 0; stp >>= 1) {
    if (threadIdx.x < stp) red[threadIdx.x] += red[threadIdx.x + stp];
    __syncthreads();
  }
  if (threadIdx.x == 0) atomicAdd(out, red[0]);
}

static __global__ void maxpool_p(const short* __restrict__ Hh, const short* __restrict__ Hl,
                                 float* __restrict__ g, int N, long long GN, int F, int Gb) {
  int wid = (int)(((long long)blockIdx.x * blockDim.x + threadIdx.x) >> 6);
  int lane = threadIdx.x & 63;
  if (wid >= Gb * F) return;
  int b = wid / F, f = wid - b * F;
  long long base = (long long)f * GN + (long long)b * N;
  float m = -INFINITY;
  for (int n = lane; n < N; n += 64) m = fmaxf(m, pget(Hh, Hl, base + n));
  for (int off = 32; off; off >>= 1) m = fmaxf(m, __shfl_down(m, off));
  if (lane == 0) g[(long long)b * F + f] = m;
}

static __global__ void fc_kernel(const float* __restrict__ in, const float* __restrict__ W,
                                 const float* __restrict__ bias, float* out,
                                 int Bc, int K, int J, int do_relu) {
  int gtid = blockIdx.x * blockDim.x + threadIdx.x;
  int wid = gtid >> 6;
  int lane = gtid & 63;
  if (wid >= Bc * J) return;
  int b = wid / J, j = wid - b * J;
  const float* ib = in + (long long)b * K;
  const float* wj = W + (long long)j * K;
  float s = 0.f;
  for (int k = lane; k < K; k += 64) s += ib[k] * wj[k];
  for (int off = 32; off > 0; off >>= 1) s += __shfl_down(s, off);
  if (lane == 0) {
    s += bias[j];
    out[wid] = do_relu ? fmaxf(s, 0.f) : s;
  }
}

static __global__ void finalize_kernel(const float* scal, float* out_regs) {
  if (threadIdx.x == 0 && blockIdx.x == 0) {
    float r1 = sqrtf(scal[0]), r2 = sqrtf(scal[1]), r3 = sqrtf(scal[2]);
    float nw = sqrtf(scal[3]), nb = sqrtf(scal[4]);
    out_regs[0] = r1; out_regs[1] = r2; out_regs[2] = r3;
    out_regs[3] = nw; out_regs[4] = nb;
    out_regs[5] = nw; out_regs[6] = nb;
    out_regs[7] = nw; out_regs[8] = nb;
  }
}

// ---------------- host orchestration ----------------

struct Ptrs {
  short *Lh, *Ll, *Tch, *Tcl, *TTh, *TTl, *Xgh, *Xgl;
  short *HTh, *HTl;
  short *W1h, *W1l, *W2h, *W2l, *W3h, *W3l;
  float *Trec, *Mm1, *Mm2, *Mm3, *sq, *dinv, *deg, *gb, *o1, *o2, *scal;
};

extern "C" void kernel_launch(void* const* d_in, const int* in_sizes, int n_in,
                              void* d_out, int out_size, void* d_ws, size_t ws_size,
                              hipStream_t stream) {
  const float* x   = (const float*)d_in[0];
  const float* w1  = (const float*)d_in[4];
  const float* b1  = (const float*)d_in[5];
  const float* w2  = (const float*)d_in[6];
  const float* b2  = (const float*)d_in[7];
  const float* w3  = (const float*)d_in[8];
  const float* b3  = (const float*)d_in[9];
  const float* fw1 = (const float*)d_in[10];
  const float* fb1 = (const float*)d_in[11];
  const float* fw2 = (const float*)d_in[12];
  const float* fb2 = (const float*)d_in[13];
  const float* fw3 = (const float*)d_in[14];
  const float* fb3 = (const float*)d_in[15];
  float* out = (float*)d_out;

  float* ws = (float*)d_ws;
  const long long NN = (long long)N_ * N_;

  Ptrs p;
  auto layout = [&](int G) -> unsigned long long {
    long long off = 0;  // floats
    auto aF = [&](long long n) { float* q = ws + off; off += (n + 7) & ~7LL; return q; };
    auto aS = [&](long long n) { short* q = (short*)(ws + off); off += (((n + 1) >> 1) + 7) & ~7LL; return q; };
    long long GN = (long long)G * N_;
    p.Lh = aS(G * NN); p.Ll = aS(G * NN);
    p.Tch = aS(GN * 1536); p.Tcl = aS(GN * 1536);
    p.TTh = aS(GN * 512); p.TTl = aS(GN * 512);
    p.Xgh = aS(GN * 32); p.Xgl = aS(GN * 32);
    p.HTh = aS(GN * 1024); p.HTl = aS(GN * 1024);
    p.W1h = aS(128 * 64); p.W1l = aS(128 * 64);
    p.W2h = aS(512 * 640); p.W2l = aS(512 * 640);
    p.W3h = aS(1024 * 1536); p.W3l = aS(1024 * 1536);
    p.Trec = aF(GN * 512);   // also aliased as single-plane LH (GN*1024 shorts)
    p.Mm1 = aF(128 * 128); p.Mm2 = aF(512 * 512); p.Mm3 = aF(1024 * 1024);
    p.sq = aF(GN); p.dinv = aF(GN); p.deg = aF(GN);
    p.gb = aF(B_ * 1024); p.o1 = aF(B_ * 512); p.o2 = aF(B_ * 128);
    p.scal = aF(16);
    return (unsigned long long)off * 4ULL;
  };
  int G = 8;
  while (G > 1 && layout(G) > ws_size) G >>= 1;
  if (layout(G) > ws_size) return;
  layout(G);
  short* LHh = (short*)p.Trec;  // GN*1024 shorts == GN*512 floats

  const long long GN = (long long)G * N_;
  auto blk1d = [](long long n) { return (int)(((n + 255) / 256 < 4096) ? (n + 255) / 256 : 4096); };

  int skSK = 64 / G; if (skSK < 1) skSK = 1;       // L1 skinny recurrence
  int rec2SK = 32 / G; if (rec2SK < 1) rec2SK = 1; // L2 recurrence (xy=16)
  int rec3SK = 8 / G; if (rec3SK < 1) rec3SK = 1;  // L3 recurrence (xy=64)
  int mm1SK = (int)(GN / 32);
  int mm2SK = 32, mm3SK = 8;

  // ---- W plane conversions (Fout x Kpad) ----
  cvt_tr_kernel<<<dim3(4, 1, 6), dim3(32, 8), 0, stream>>>(
      w1, 128, 6LL * 128, p.W1h, p.W1l, 64, 6, 6, 128);
  pad0_kernel<<<blk1d(128LL * 28), 256, 0, stream>>>(p.W1h, p.W1l, 64, 128, 36, 64);
  cvt_tr_kernel<<<dim3(16, 4, 5), dim3(32, 8), 0, stream>>>(
      w2, 512, 128LL * 512, p.W2h, p.W2l, 640, 128, 128, 512);
  cvt_tr_kernel<<<dim3(32, 16, 3), dim3(32, 8), 0, stream>>>(
      w3, 1024, 512LL * 1024, p.W3h, p.W3l, 1536, 512, 512, 1024);
  pad0_kernel<<<blk1d(GN * 26), 256, 0, stream>>>(p.Xgh, p.Xgl, 32, GN, 6, 32);

  zerof_kernel<<<1, 256, 0, stream>>>(p.scal, 16);
  zerof_kernel<<<64, 256, 0, stream>>>(p.Mm1, 128LL * 128);
  zerof_kernel<<<256, 256, 0, stream>>>(p.Mm2, 512LL * 512);
  zerof_kernel<<<1024, 256, 0, stream>>>(p.Mm3, 1024LL * 1024);

  auto do_layer = [&](const float* Xrm, int Fin, int taps, int Fout, const float* bias,
                      const short* Wh, const short* Wl, int Kpad,
                      int recSK, int mmSK, float* Mm) {
    // ---- prep: Tcat slot0, sq, T0^T ----
    if (Xrm) {
      rowsq_small<<<blk1d(GN), 256, 0, stream>>>(Xrm, p.sq, 6, GN);
      cvt_rm_kernel<<<blk1d(GN * 6), 256, 0, stream>>>(Xrm, 6, p.Tch, p.Tcl, 64, GN, 6);
      pad0_kernel<<<blk1d(GN * 28), 256, 0, stream>>>(p.Tch, p.Tcl, 64, GN, 36, 64);
      cvt_rm_kernel<<<blk1d(GN * 6), 256, 0, stream>>>(Xrm, 6, p.Xgh, p.Xgl, 32, GN, 6);
      cvt_tr_kernel<<<dim3(1, 64, G), dim3(32, 8), 0, stream>>>(
          Xrm, 6, (long long)N_ * 6, p.TTh, p.TTl, GN, N_, N_, 6);
    } else {
      tr_pp_kernel<<<dim3((int)(GN / 32), Fin / 32), dim3(32, 8), 0, stream>>>(
          p.HTh, p.HTl, GN, p.Tch, p.Tcl, Kpad, Fin, GN);
    }
    // ---- graph (mode 5) -> L split planes + deg ----
    zerof_kernel<<<blk1d(GN), 256, 0, stream>>>(p.deg, GN);
    const short* Gh = Xrm ? p.Xgh : p.Tch;
    const short* Gl = Xrm ? p.Xgl : p.Tcl;
    int glda = Xrm ? 32 : Kpad;
    int GK = Xrm ? 32 : Fin;
    gemm_mf<0><<<dim3(16, 16, G), 256, 0, stream>>>(
        Gh, Gl, glda, (long long)N_ * glda, Gh, Gl, glda, (long long)N_ * glda,
        nullptr, nullptr, 0, 0,
        nullptr, p.Lh, p.Ll, N_, NN,
        N_, GK, N_, 1.f, 0.f, 5, p.sq, N_, p.deg, 1, nullptr);
    dinv_from_deg<<<blk1d(GN), 256, 0, stream>>>(p.deg, p.dinv, GN);
    scaleL_p<<<4096, 256, 0, stream>>>(p.Lh, p.Ll, p.dinv, G * NN);
    // ---- chebyshev recurrence (mode 2 + cvt_dual) ----
    for (int k = 1; k < taps; ++k) {
      zerof_kernel<<<blk1d(GN * Fin), 256, 0, stream>>>(p.Trec, GN * Fin);
      const short* Bh_ = (k == 1 && !Xrm) ? p.HTh : p.TTh;
      const short* Bl_ = (k == 1 && !Xrm) ? p.HTl : p.TTl;
      if (Fin == 6) {
        gemm_skinny<<<dim3(1, 16, G * skSK), 256, 0, stream>>>(
            p.Lh, p.Ll, N_, NN, p.TTh, p.TTl, GN, N_,
            p.Trec, 6, (long long)N_ * 6, N_, N_, 6, skSK);
        cvt_dual_m<<<blk1d(GN * 6), 256, 0, stream>>>(
            p.Trec, (k == 2) ? Xrm : nullptr,
            (k > 2) ? p.Tch + (long long)(k - 2) * 6 : nullptr,
            (k > 2) ? p.Tcl + (long long)(k - 2) * 6 : nullptr,
            p.Tch + (long long)k * 6, p.Tcl + (long long)k * 6,
            p.TTh, p.TTl, GN, (k == 1) ? 1.f : 2.f, (k == 1) ? 0.f : -1.f);
      } else {
        gemm_mf<0><<<dim3(Fin / 128, 16, G * recSK), 256, 0, stream>>>(
            p.Lh, p.Ll, N_, NN, Bh_, Bl_, (int)GN, N_,
            nullptr, nullptr, 0, 0,
            p.Trec, nullptr, nullptr, Fin, (long long)N_ * Fin,
            N_, N_, Fin, 1.f, 0.f, 2, nullptr, 0, nullptr, recSK, nullptr);
        cvt_dual_d<<<dim3(Fin / 32, (int)(GN / 32)), dim3(32, 8), 0, stream>>>(
            p.Trec, Fin,
            (k >= 2) ? p.Tch + (long long)(k - 2) * Fin : nullptr,
            (k >= 2) ? p.Tcl + (long long)(k - 2) * Fin : nullptr, Kpad,
            p.Tch + (long long)k * Fin, p.Tcl + (long long)k * Fin, Kpad,
            p.TTh, p.TTl, GN, GN, Fin, (k == 1) ? 1.f : 2.f);
      }
    }
    // ---- projection (mode 4): HT = relu(Wcat^T @ Tcat^T + bias), sq atomics ----
    zerof_kernel<<<blk1d(GN), 256, 0, stream>>>(p.sq, GN);
    gemm_mf<0><<<dim3((int)(GN / 128), Fout / 128, 1), 256, 0, stream>>>(
        Wh, Wl, Kpad, 0, p.Tch, p.Tcl, Kpad, 0,
        nullptr, nullptr, 0, 0,
        nullptr, p.HTh, p.HTl, (int)GN, 0,
        Fout, Kpad, (int)GN, 1.f, 0.f, 4, nullptr, 0, p.sq, 1, bias);
    // ---- LHT = H^T L + H^T (mode 3, B = L hi-plane only, LH single-plane out) ----
    gemm_mf<1><<<dim3(16, Fout / 128, G), 256, 0, stream>>>(
        p.HTh, p.HTl, (int)GN, N_, p.Lh, nullptr, N_, NN,
        p.HTh, p.HTl, (int)GN, N_,
        nullptr, LHh, nullptr, (int)GN, N_,
        Fout, N_, N_, 1.f, 1.f, 3, nullptr, 0, nullptr, 1, nullptr);
    // ---- Mm += H^T (L+I) H (mode 2, B = LH single) ----
    gemm_mf<1><<<dim3(Fout / 128, Fout / 128, mmSK), 256, 0, stream>>>(
        p.HTh, p.HTl, (int)GN, 0, LHh, nullptr, (int)GN, 0,
        nullptr, nullptr, 0, 0,
        Mm, nullptr, nullptr, Fout, 0,
        Fout, (int)GN, Fout, 1.f, 0.f, 2, nullptr, 0, nullptr, mmSK, nullptr);
  };

  for (int c = 0; c < B_ / G; ++c) {
    const float* Xc = x + (long long)c * GN * 6;
    do_layer(Xc, 6, 6, 128, b1, p.W1h, p.W1l, 64, 1, mm1SK, p.Mm1);
    do_layer(nullptr, 128, 5, 512, b2, p.W2h, p.W2l, 640, rec2SK, mm2SK, p.Mm2);
    do_layer(nullptr, 512, 3, 1024, b3, p.W3h, p.W3l, 1536, rec3SK, mm3SK, p.Mm3);
    maxpool_p<<<(G * 1024 * 64 + 255) / 256, 256, 0, stream>>>(
        p.HTh, p.HTl, p.gb + (long long)c * G * 1024, N_, GN, 1024, G);
  }

  sumsq_kernel<<<64, 256, 0, stream>>>(p.Mm1, 128LL * 128, p.scal + 0);
  sumsq_kernel<<<256, 256, 0, stream>>>(p.Mm2, 512LL * 512, p.scal + 1);
  sumsq_kernel<<<256, 256, 0, stream>>>(p.Mm3, 1024LL * 1024, p.scal + 2);

  fc_kernel<<<(B_ * 512 * 64 + 255) / 256, 256, 0, stream>>>(p.gb, fw1, fb1, p.o1, B_, 1024, 512, 1);
  fc_kernel<<<(B_ * 128 * 64 + 255) / 256, 256, 0, stream>>>(p.o1, fw2, fb2, p.o2, B_, 512, 128, 1);
  fc_kernel<<<(B_ * 10 * 64 + 255) / 256, 256, 0, stream>>>(p.o2, fw3, fb3, out, B_, 128, 10, 0);

  sumsq_kernel<<<256, 256, 0, stream>>>(fw1, 512LL * 1024, p.scal + 3);
  sumsq_kernel<<<1, 256, 0, stream>>>(fb1, 512LL, p.scal + 4);
  finalize_kernel<<<1, 64, 0, stream>>>(p.scal, out + 160);
}